// Round 2
// baseline (791.814 us; speedup 1.0000x reference)
//
#include <hip/hip_runtime.h>
#include <math.h>

// AudioPreprocessingLayer: hamming * x -> rfft(512, norm=forward).real^2
//   -> mel(20x257) -> where(==0, 2^-52) -> floor(log2)
//
// floor(log2) tolerates ZERO boundary flips vs the harness's numpy reference,
// so the whole chain runs in float64 (agrees with an f64 reference to ~1e-14
// relative; flip probability ~1e-7 across 2.6M outputs).
//
// One frame (512 fp32 samples) per 256-thread block.
// Real FFT via packed 256-pt complex Stockham DIF FFT (f64) in LDS.

__global__ void twiddle_kernel(double* __restrict__ tw) {
    const int t = threadIdx.x;  // 256 threads
    double s, c;
    sincospi((double)t * (1.0 / 256.0), &s, &c);  // theta = pi*t/256
    tw[t]       = c;
    tw[256 + t] = s;
}

__global__ __launch_bounds__(256) void audio_mel_kernel(
    const float*  __restrict__ x,    // (131072, 512) f32
    const float*  __restrict__ fb,   // (20, 257)     f32
    const float*  __restrict__ hw,   // (512,)        f32
    const double* __restrict__ tw,   // (512,) f64: cos[256] then sin[256]
    float* __restrict__ out)         // (131072, 20)  f32
{
    __shared__ double Are[256], Aim[256], Bre[256], Bim[256];
    __shared__ double ltc[256], lts[256];   // cos/sin(pi*k/256), f64
    __shared__ double pwr[257];

    const int t = threadIdx.x;
    const int f = blockIdx.x;

    ltc[t] = tw[t];
    lts[t] = tw[256 + t];

    // Load 2 consecutive samples -> one complex point (even->re, odd->im),
    // window fused. Upcast to f64 AFTER loading the given fp32 values
    // (matches an f64 numpy recompute from the same inputs).
    {
        const float2 xv = ((const float2*)x)[(size_t)f * 256 + t];
        const float2 hv = ((const float2*)hw)[t];
        Are[t] = (double)xv.x * (double)hv.x;
        Aim[t] = (double)xv.y * (double)hv.y;
    }
    __syncthreads();

    // 256-point Stockham DIF FFT (natural in/out), 8 radix-2 stages, f64.
    // which = t>>7 is wave-uniform -> no divergence.
    double* sre = Are; double* sim = Aim;
    double* dre = Bre; double* dim = Bim;
    const int p = t & 127;
    const int which = t >> 7;
#pragma unroll
    for (int s = 0; s < 8; s++) {
        const int j = p >> s;
        const double ar = sre[p],       ai = sim[p];
        const double br = sre[p + 128], bi = sim[p + 128];
        double orr, oi;
        int dpos;
        if (which) {
            // w = e^{-i*pi*j/(128>>s)} -> table index j << (s+1)
            const int idx = j << (s + 1);
            const double wr = ltc[idx];
            const double wi = -lts[idx];
            const double ur = ar - br, ui = ai - bi;
            orr = wr * ur - wi * ui;
            oi  = wr * ui + wi * ur;
            dpos = p + ((j + 1) << s);
        } else {
            orr = ar + br;
            oi  = ai + bi;
            dpos = p + (j << s);
        }
        dre[dpos] = orr;
        dim[dpos] = oi;
        __syncthreads();
        double* tmp;
        tmp = sre; sre = dre; dre = tmp;
        tmp = sim; sim = dim; dim = tmp;
    }
    // After 8 stages (even count) the result sits back in A (sre/sim).

    // Untangle packed FFT -> Re(rfft)_k, forward norm 1/512, square.
    // Re X_k = (a+c)/2 + cos(th)*(b+d)/2 - sin(th)*(a-c)/2,  th = pi*k/256
    {
        const double a = sre[t], b = sim[t];
        const int t2 = (256 - t) & 255;
        const double c = sre[t2], d = sim[t2];
        const double rex = 0.5 * (a + c)
                         + 0.5 * (ltc[t] * (b + d) - lts[t] * (a - c));
        const double v = rex * (1.0 / 512.0);
        pwr[t] = v * v;
        if (t == 0) {
            // k = 256 (Nyquist): Re X_256 = Re Z_0 - Im Z_0
            const double vn = (a - b) * (1.0 / 512.0);
            pwr[256] = vn * vn;
        }
    }
    __syncthreads();

    // Mel projection: 20 mels x 257 bins; 8 threads per mel (3 waves active).
    if (t < 160) {
        const int mel = t >> 3;
        const int sub = t & 7;
        const float* wrow = fb + mel * 257;
        double acc = 0.0;
        for (int k = sub; k < 257; k += 8)
            acc = fma((double)wrow[k], pwr[k], acc);
        acc += __shfl_down(acc, 4, 8);
        acc += __shfl_down(acc, 2, 8);
        acc += __shfl_down(acc, 1, 8);
        if (sub == 0) {
            double v = acc;
            if (v == 0.0) v = 2.220446049250313e-16;  // float64 eps = 2^-52
            out[(size_t)f * 20 + mel] = (float)floor(log2(v));
        }
    }
}

extern "C" void kernel_launch(void* const* d_in, const int* in_sizes, int n_in,
                              void* d_out, int out_size, void* d_ws, size_t ws_size,
                              hipStream_t stream) {
    const float* x  = (const float*)d_in[0];   // (4096, 32, 512) f32
    const float* fb = (const float*)d_in[1];   // (20, 257) f32
    const float* hw = (const float*)d_in[2];   // (512,) f32
    float* out = (float*)d_out;                // (4096, 32, 20, 1) f32
    double* tw = (double*)d_ws;                // 512 doubles = 4 KiB scratch

    twiddle_kernel<<<1, 256, 0, stream>>>(tw);

    const int frames = in_sizes[0] / 512;      // 131072
    audio_mel_kernel<<<frames, 256, 0, stream>>>(x, fb, hw, tw, out);
}

// Round 3
// 545.066 us; speedup vs baseline: 1.4527x; 1.4527x over previous
//
#include <hip/hip_runtime.h>
#include <math.h>

// AudioPreprocessingLayer: hamming * x -> rfft(512, norm=forward).real^2
//   -> mel(20x257) -> where(==0, 2^-52) -> floor(log2)
//
// Hybrid scheme:
//   prep:   twiddle tables (f64 + f32) and padded filter bank -> ws
//   phase1: fp32 pipeline (fused radix-2^2 Stockham, 1 wave/frame,
//           4 frames/block); flags frames whose log2(mel) is within 1e-3
//           of an integer (fp32 error ~1.5e-4 -> 6x margin) or mel<1e-30
//   phase2: flagged frames (~5%) recomputed with the R2-validated f64
//           pipeline (8 frames/block, block-uniform gating), overwriting
//           their 20 outputs. Flags rewritten every call -> poison-safe.

#define MARGIN_L2 1.0e-3f

__device__ __forceinline__ float2 cmulc(float2 w, float2 z) {
    // w = (cos, sin) meaning e^{-i*theta}: (c*zr + s*zi, c*zi - s*zr)
    return make_float2(w.x * z.x + w.y * z.y, w.x * z.y - w.y * z.x);
}

// ---------------------------------------------------------------- prep ----
__global__ void prep_full(const float* __restrict__ fb,
                          double* __restrict__ tw64,
                          float2* __restrict__ tw32,
                          float* __restrict__ fbP) {
    const int t = threadIdx.x;  // 256
    double s, c;
    sincospi((double)t * (1.0 / 256.0), &s, &c);
    tw64[t]       = c;
    tw64[256 + t] = s;
    tw32[t] = make_float2((float)c, (float)s);
    for (int i = t; i < 20 * 264; i += 256) {
        const int m = i / 264, k = i % 264;
        fbP[i] = (k < 257) ? fb[m * 257 + k] : 0.0f;  // rows padded to 264
    }
}

__global__ void prep_tw64(double* __restrict__ tw64) {
    const int t = threadIdx.x;
    double s, c;
    sincospi((double)t * (1.0 / 256.0), &s, &c);
    tw64[t]       = c;
    tw64[256 + t] = s;
}

// -------------------------------------------------------------- phase 1 ----
// fp32: 4 frames per 256-thread block, one wave (64 lanes) per frame.
__global__ __launch_bounds__(256) void phase1(
    const float* __restrict__ x,      // (frames, 512)
    const float* __restrict__ hw,     // (512,)
    const float2* __restrict__ tw32,  // (256,) (cos, sin) of pi*k/256
    const float* __restrict__ fbP,    // (20, 264) padded filter bank (ws)
    float* __restrict__ out,          // (frames, 20)
    unsigned char* __restrict__ flags)// (frames,)
{
    __shared__ __align__(16) float2 A[4][256];
    __shared__ __align__(16) float2 B[4][256];   // also holds pwr[264] per frame
    __shared__ __align__(16) float2 tw[256];
    __shared__ __align__(16) float fbL[20 * 264];

    const int t = threadIdx.x;
    const int w = t >> 6;     // wave id = frame slot
    const int l = t & 63;     // lane
    const int fg = blockIdx.x * 4 + w;

    tw[t] = tw32[t];
    for (int i = t; i < 20 * 264; i += 256) fbL[i] = fbP[i];

    // load + window (wave-private): lane l covers positions l+64*i
    {
        const float2* xf = (const float2*)x + (size_t)fg * 256;
        const float2* hwf = (const float2*)hw;
#pragma unroll
        for (int i = 0; i < 4; i++) {
            const int p = l + 64 * i;
            const float2 xv = xf[p];
            const float2 hv = hwf[p];
            A[w][p] = make_float2(xv.x * hv.x, xv.y * hv.y);
        }
    }
    __syncthreads();   // tw/fbL ready (A is wave-private)

    // 4 fused radix-2^2 stages (s = 0,2,4,6). Composition of the validated
    // radix-2 Stockham stages:
    //   stage s: j=p>>s; lo: d[p+(j<<s)]=a+b; hi: d[p+((j+1)<<s)]=w*(a-b),
    //   w = e^{-i*pi*(j<<(s+1))/256}. Fused thread (j'=l>>s, r=l&(2^s-1))
    //   handles stage-s butterflies j' and j'+2^(6-s) (twiddles w1, -i*w1)
    //   plus the two stage-(s+1) butterflies they feed (twiddle w2).
    float2* src = &A[w][0];
    float2* dst = &B[w][0];
#pragma unroll
    for (int s = 0; s < 8; s += 2) {
        const int j = l >> s;
        const int r = l & ((1 << s) - 1);
        const float2 x1 = src[l];
        const float2 y1 = src[l + 128];
        const float2 x2 = src[l + 64];
        const float2 y2 = src[l + 192];
        const float2 w1 = tw[j << (s + 1)];
        const float2 w2 = tw[j << (s + 2)];
        // stage s
        const float2 u1 = make_float2(x1.x + y1.x, x1.y + y1.y);
        const float2 d1 = make_float2(x1.x - y1.x, x1.y - y1.y);
        const float2 v1 = cmulc(w1, d1);
        const float2 u2 = make_float2(x2.x + y2.x, x2.y + y2.y);
        const float2 d2 = make_float2(x2.x - y2.x, x2.y - y2.y);
        const float2 m  = cmulc(w1, d2);
        const float2 v2 = make_float2(m.y, -m.x);    // -i * m
        // stage s+1
        const float2 o0 = make_float2(u1.x + u2.x, u1.y + u2.y);
        const float2 e1 = make_float2(u1.x - u2.x, u1.y - u2.y);
        const float2 o1 = cmulc(w2, e1);
        const float2 o2 = make_float2(v1.x + v2.x, v1.y + v2.y);
        const float2 e3 = make_float2(v1.x - v2.x, v1.y - v2.y);
        const float2 o3 = cmulc(w2, e3);
        const int eb = (j << (s + 2)) + r;
        dst[eb]            = o0;
        dst[eb + (1 << s)] = o2;   // e_base + 2^s
        dst[eb + (2 << s)] = o1;   // e_base + 2^(s+1)
        dst[eb + (3 << s)] = o3;
        __syncthreads();
        float2* tmp = src; src = dst; dst = tmp;
    }
    // result (natural order) now in A[w]; B[w] is free -> pwr lives there.

    // Untangle -> Re(rfft)_k, /512, square. Validated formula:
    // Re X_k = (a+c)/2 + (cos*(b+d) - sin*(a-c))/2 with (a,b)=Z[k],(c,d)=Z[256-k]
    {
        float* pwr = (float*)&B[w][0];    // 264 floats
        const float2* Z = src;            // == A[w]
#pragma unroll
        for (int i = 0; i < 4; i++) {
            const int k = l + 64 * i;
            const float2 zk = Z[k];
            const float2 zc = Z[(256 - k) & 255];
            const float2 wk = tw[k];
            const float rex = 0.5f * (zk.x + zc.x)
                            + 0.5f * (wk.x * (zk.y + zc.y) - wk.y * (zk.x - zc.x));
            const float v = rex * (1.0f / 512.0f);
            pwr[k] = v * v;
        }
        if (l == 0) {
            const float2 z0 = Z[0];
            const float vn = (z0.x - z0.y) * (1.0f / 512.0f);
            pwr[256] = vn * vn;
        }
        if (l >= 57) pwr[257 + (l - 57)] = 0.0f;   // zero pad 257..263
    }
    __syncthreads();   // all 4 frames' pwr ready

    // Mel partials: 240 threads = 3 subranges x 80 (frame,mel) pairs.
    // part[] and fflag[] alias A (dead after untangle).
    float* part = (float*)&A[0][0];                 // 240 floats
    int* fflag = (int*)((char*)&A[0][0] + 960);     // 4 ints
    if (t >= 240 && t < 244) fflag[t - 240] = 0;
    if (t < 240) {
        const int sub = t / 80;
        const int pr  = t % 80;
        const int fr  = pr / 20;
        const int mel = pr % 20;
        const float* pw = (const float*)&B[fr][0];
        const float* wrow = fbL + mel * 264;
        const int k0 = sub * 88;                    // 88*4B = 16B-aligned
        float acc = 0.0f;
#pragma unroll
        for (int k = k0; k < k0 + 88; k += 4) {     // pads are 0 on both sides
            const float4 p4 = *(const float4*)(pw + k);
            const float4 w4 = *(const float4*)(wrow + k);
            acc = fmaf(w4.x, p4.x, fmaf(w4.y, p4.y,
                  fmaf(w4.z, p4.z, fmaf(w4.w, p4.w, acc))));
        }
        part[t] = acc;
    }
    __syncthreads();

    if (t < 80) {
        const float v = part[t] + part[t + 80] + part[t + 160];
        const int fr = t / 20, mel = t % 20;
        float fl;
        int flag;
        if (v < 1e-30f) {                // includes v==0; fp32 underflow risk
            fl = -52.0f;
            flag = 1;
        } else {
            const float l2 = log2f(v);
            fl = floorf(l2);
            flag = (l2 - fl < MARGIN_L2) | ((fl + 1.0f - l2) < MARGIN_L2);
        }
        out[(size_t)(blockIdx.x * 4 + fr) * 20 + mel] = fl;
        if (flag) atomicOr(&fflag[fr], 1);
    }
    __syncthreads();
    if (t < 4) flags[blockIdx.x * 4 + t] = (unsigned char)fflag[t];
}

// -------------------------------------------------------------- phase 2 ----
// f64 repair of flagged frames (R2-validated pipeline), 8 frames/block.
__global__ __launch_bounds__(256) void phase2_fix(
    const float* __restrict__ x,
    const float* __restrict__ fb,
    const float* __restrict__ hw,
    const double* __restrict__ tw64,
    const unsigned char* __restrict__ flags,
    float* __restrict__ out)
{
    __shared__ double Are[256], Aim[256], Bre[256], Bim[256];
    __shared__ double ltc[256], lts[256];
    __shared__ double pwr[257];

    const int t = threadIdx.x;
    ltc[t] = tw64[t];
    lts[t] = tw64[256 + t];

    for (int r = 0; r < 8; r++) {
        const int f = blockIdx.x * 8 + r;
        if (!flags[f]) continue;          // block-uniform branch
        __syncthreads();                  // LDS reuse + first-use of ltc/lts

        {
            const float2 xv = ((const float2*)x)[(size_t)f * 256 + t];
            const float2 hv = ((const float2*)hw)[t];
            Are[t] = (double)xv.x * (double)hv.x;
            Aim[t] = (double)xv.y * (double)hv.y;
        }
        __syncthreads();

        double* sre = Are; double* sim = Aim;
        double* dre = Bre; double* dim = Bim;
        const int p = t & 127;
        const int which = t >> 7;
#pragma unroll
        for (int s = 0; s < 8; s++) {
            const int j = p >> s;
            const double ar = sre[p],       ai = sim[p];
            const double br = sre[p + 128], bi = sim[p + 128];
            double orr, oi;
            int dpos;
            if (which) {
                const int idx = j << (s + 1);
                const double wr = ltc[idx];
                const double wi = -lts[idx];
                const double ur = ar - br, ui = ai - bi;
                orr = wr * ur - wi * ui;
                oi  = wr * ui + wi * ur;
                dpos = p + ((j + 1) << s);
            } else {
                orr = ar + br;
                oi  = ai + bi;
                dpos = p + (j << s);
            }
            dre[dpos] = orr;
            dim[dpos] = oi;
            __syncthreads();
            double* tmp;
            tmp = sre; sre = dre; dre = tmp;
            tmp = sim; sim = dim; dim = tmp;
        }

        {
            const double a = sre[t], b = sim[t];
            const int t2 = (256 - t) & 255;
            const double c = sre[t2], d = sim[t2];
            const double rex = 0.5 * (a + c)
                             + 0.5 * (ltc[t] * (b + d) - lts[t] * (a - c));
            const double v = rex * (1.0 / 512.0);
            pwr[t] = v * v;
            if (t == 0) {
                const double vn = (a - b) * (1.0 / 512.0);
                pwr[256] = vn * vn;
            }
        }
        __syncthreads();

        if (t < 160) {
            const int mel = t >> 3;
            const int sub = t & 7;
            const float* wrow = fb + mel * 257;
            double acc = 0.0;
            for (int k = sub; k < 257; k += 8)
                acc = fma((double)wrow[k], pwr[k], acc);
            acc += __shfl_down(acc, 4, 8);
            acc += __shfl_down(acc, 2, 8);
            acc += __shfl_down(acc, 1, 8);
            if (sub == 0) {
                double v = acc;
                if (v == 0.0) v = 2.220446049250313e-16;
                out[(size_t)f * 20 + mel] = (float)floor(log2(v));
            }
        }
        __syncthreads();
    }
}

// ------------------------------------------------- fallback: all-f64 (R2) ----
__global__ __launch_bounds__(256) void f64_all(
    const float*  __restrict__ x,
    const float*  __restrict__ fb,
    const float*  __restrict__ hw,
    const double* __restrict__ tw,
    float* __restrict__ out)
{
    __shared__ double Are[256], Aim[256], Bre[256], Bim[256];
    __shared__ double ltc[256], lts[256];
    __shared__ double pwr[257];

    const int t = threadIdx.x;
    const int f = blockIdx.x;

    ltc[t] = tw[t];
    lts[t] = tw[256 + t];
    {
        const float2 xv = ((const float2*)x)[(size_t)f * 256 + t];
        const float2 hv = ((const float2*)hw)[t];
        Are[t] = (double)xv.x * (double)hv.x;
        Aim[t] = (double)xv.y * (double)hv.y;
    }
    __syncthreads();

    double* sre = Are; double* sim = Aim;
    double* dre = Bre; double* dim = Bim;
    const int p = t & 127;
    const int which = t >> 7;
#pragma unroll
    for (int s = 0; s < 8; s++) {
        const int j = p >> s;
        const double ar = sre[p],       ai = sim[p];
        const double br = sre[p + 128], bi = sim[p + 128];
        double orr, oi;
        int dpos;
        if (which) {
            const int idx = j << (s + 1);
            const double wr = ltc[idx];
            const double wi = -lts[idx];
            const double ur = ar - br, ui = ai - bi;
            orr = wr * ur - wi * ui;
            oi  = wr * ui + wi * ur;
            dpos = p + ((j + 1) << s);
        } else {
            orr = ar + br;
            oi  = ai + bi;
            dpos = p + (j << s);
        }
        dre[dpos] = orr;
        dim[dpos] = oi;
        __syncthreads();
        double* tmp;
        tmp = sre; sre = dre; dre = tmp;
        tmp = sim; sim = dim; dim = tmp;
    }

    {
        const double a = sre[t], b = sim[t];
        const int t2 = (256 - t) & 255;
        const double c = sre[t2], d = sim[t2];
        const double rex = 0.5 * (a + c)
                         + 0.5 * (ltc[t] * (b + d) - lts[t] * (a - c));
        const double v = rex * (1.0 / 512.0);
        pwr[t] = v * v;
        if (t == 0) {
            const double vn = (a - b) * (1.0 / 512.0);
            pwr[256] = vn * vn;
        }
    }
    __syncthreads();

    if (t < 160) {
        const int mel = t >> 3;
        const int sub = t & 7;
        const float* wrow = fb + mel * 257;
        double acc = 0.0;
        for (int k = sub; k < 257; k += 8)
            acc = fma((double)wrow[k], pwr[k], acc);
        acc += __shfl_down(acc, 4, 8);
        acc += __shfl_down(acc, 2, 8);
        acc += __shfl_down(acc, 1, 8);
        if (sub == 0) {
            double v = acc;
            if (v == 0.0) v = 2.220446049250313e-16;
            out[(size_t)f * 20 + mel] = (float)floor(log2(v));
        }
    }
}

// ---------------------------------------------------------------- launch ----
extern "C" void kernel_launch(void* const* d_in, const int* in_sizes, int n_in,
                              void* d_out, int out_size, void* d_ws, size_t ws_size,
                              hipStream_t stream) {
    const float* x  = (const float*)d_in[0];   // (4096, 32, 512) f32
    const float* fb = (const float*)d_in[1];   // (20, 257) f32
    const float* hw = (const float*)d_in[2];   // (512,) f32
    float* out = (float*)d_out;

    const int frames = in_sizes[0] / 512;      // 131072

    char* ws = (char*)d_ws;
    double* tw64 = (double*)ws;                          // 4096 B
    float2* tw32 = (float2*)(ws + 4096);                 // 2048 B
    float*  fbP  = (float*)(ws + 6144);                  // 21120 B
    unsigned char* flags = (unsigned char*)(ws + 32768); // frames B

    const size_t WS_NEEDED = 32768 + (size_t)frames;
    if (ws_size >= WS_NEEDED && (frames % 8) == 0) {
        prep_full<<<1, 256, 0, stream>>>(fb, tw64, tw32, fbP);
        phase1<<<frames / 4, 256, 0, stream>>>(x, hw, tw32, fbP, out, flags);
        phase2_fix<<<frames / 8, 256, 0, stream>>>(x, fb, hw, tw64, flags, out);
    } else {
        prep_tw64<<<1, 256, 0, stream>>>(tw64);
        f64_all<<<frames, 256, 0, stream>>>(x, fb, hw, tw64, out);
    }
}

// Round 4
// 518.334 us; speedup vs baseline: 1.5276x; 1.0516x over previous
//
#include <hip/hip_runtime.h>
#include <math.h>

// AudioPreprocessingLayer: hamming * x -> rfft(512, norm=forward).real^2
//   -> mel(20x257) -> where(==0, 2^-52) -> floor(log2)
//
// Hybrid scheme (R3-validated math, restructured for occupancy/barriers):
//   prep:   twiddle tables (f64+f32), padded filter bank, worklist count=0
//   phase1: fp32, 1 wave/frame, 4 frames/block, ONE barrier total.
//           FFT/untangle/mel are wave-private (in-wave DS ordering).
//           Frames with any log2(mel) within 1e-3 of an integer (or
//           mel<1e-30) are appended to a compacted worklist.
//   phase2: fixed 2048 blocks grid-stride the worklist; each flagged frame
//           (~4%) recomputed with the R2-validated f64 pipeline.

#define MARGIN_L2 1.0e-3f

__device__ __forceinline__ float2 cmulc(float2 w, float2 z) {
    // w = (cos, sin) meaning e^{-i*theta}
    return make_float2(w.x * z.x + w.y * z.y, w.x * z.y - w.y * z.x);
}

// ---------------------------------------------------------------- prep ----
__global__ void prep_full(const float* __restrict__ fb,
                          double* __restrict__ tw64,
                          float2* __restrict__ tw32,
                          float* __restrict__ fbP,
                          unsigned* count) {
    const int t = threadIdx.x;  // 256
    double s, c;
    sincospi((double)t * (1.0 / 256.0), &s, &c);
    tw64[t]       = c;
    tw64[256 + t] = s;
    tw32[t] = make_float2((float)c, (float)s);
    for (int i = t; i < 20 * 264; i += 256) {
        const int m = i / 264, k = i % 264;
        fbP[i] = (k < 257) ? fb[m * 257 + k] : 0.0f;  // rows padded to 264
    }
    if (count && t == 0) *count = 0;
}

__global__ void prep_tw64(double* __restrict__ tw64) {
    const int t = threadIdx.x;
    double s, c;
    sincospi((double)t * (1.0 / 256.0), &s, &c);
    tw64[t]       = c;
    tw64[256 + t] = s;
}

// -------------------------------------------------------------- phase 1 ----
// fp32: 4 frames per 256-thread block, one wave (64 lanes) per frame.
// A/B/pwr are wave-private -> no barriers needed around them (DS ops from
// one wave execute in order); only the shared tw table needs one barrier.
__global__ __launch_bounds__(256, 8) void phase1(
    const float* __restrict__ x,      // (frames, 512)
    const float* __restrict__ hw,     // (512,)
    const float2* __restrict__ tw32,  // (256,) (cos,sin) of pi*k/256 (ws)
    const float* __restrict__ fbP,    // (20, 264) padded filter bank (ws)
    float* __restrict__ out,          // (frames, 20)
    unsigned char* __restrict__ flags,// (frames,) -- tier-2 path only
    unsigned* __restrict__ count,     // worklist count -- tier-1 path only
    unsigned* __restrict__ worklist)  // flagged frame ids -- tier-1 only
{
    __shared__ __align__(16) float2 A[4][256];
    __shared__ __align__(16) float2 B[4][256];   // later: pwr[264] per frame
    __shared__ __align__(16) float2 tw[256];

    const int t = threadIdx.x;
    const int w = t >> 6;     // wave id = frame slot
    const int l = t & 63;     // lane
    const int fg = blockIdx.x * 4 + w;

    tw[t] = tw32[t];

    // load + window: float4 = 4 samples = 2 complex points per load.
    {
        const float4* xf4 = (const float4*)(x + (size_t)fg * 512);
        const float4* hf4 = (const float4*)hw;
        float4* A4 = (float4*)&A[w][0];
#pragma unroll
        for (int i = 0; i < 2; i++) {
            const int j = l + 64 * i;
            const float4 xv = xf4[j];
            const float4 hv = hf4[j];
            A4[j] = make_float4(xv.x * hv.x, xv.y * hv.y,
                                xv.z * hv.z, xv.w * hv.w);
        }
    }
    __syncthreads();   // tw ready (A is wave-private)
    __builtin_amdgcn_wave_barrier();

    // 4 fused radix-2^2 Stockham stages (validated in R3).
    float2* src = &A[w][0];
    float2* dst = &B[w][0];
#pragma unroll
    for (int s = 0; s < 8; s += 2) {
        const int j = l >> s;
        const int r = l & ((1 << s) - 1);
        const float2 x1 = src[l];
        const float2 y1 = src[l + 128];
        const float2 x2 = src[l + 64];
        const float2 y2 = src[l + 192];
        const float2 w1 = tw[j << (s + 1)];
        const float2 w2 = tw[j << (s + 2)];
        const float2 u1 = make_float2(x1.x + y1.x, x1.y + y1.y);
        const float2 d1 = make_float2(x1.x - y1.x, x1.y - y1.y);
        const float2 v1 = cmulc(w1, d1);
        const float2 u2 = make_float2(x2.x + y2.x, x2.y + y2.y);
        const float2 d2 = make_float2(x2.x - y2.x, x2.y - y2.y);
        const float2 m  = cmulc(w1, d2);
        const float2 v2 = make_float2(m.y, -m.x);    // -i * m
        const float2 o0 = make_float2(u1.x + u2.x, u1.y + u2.y);
        const float2 e1 = make_float2(u1.x - u2.x, u1.y - u2.y);
        const float2 o1 = cmulc(w2, e1);
        const float2 o2 = make_float2(v1.x + v2.x, v1.y + v2.y);
        const float2 e3 = make_float2(v1.x - v2.x, v1.y - v2.y);
        const float2 o3 = cmulc(w2, e3);
        const int eb = (j << (s + 2)) + r;
        dst[eb]            = o0;
        dst[eb + (1 << s)] = o2;
        dst[eb + (2 << s)] = o1;
        dst[eb + (3 << s)] = o3;
        __builtin_amdgcn_wave_barrier();   // in-wave DS order; pin compiler
        float2* tmp = src; src = dst; dst = tmp;
    }
    // result (natural order) in A[w]; B[w] free -> pwr lives there.

    float* pwr = (float*)&B[w][0];    // 264 floats
    {
        const float2* Z = src;        // == A[w]
#pragma unroll
        for (int i = 0; i < 4; i++) {
            const int k = l + 64 * i;
            const float2 zk = Z[k];
            const float2 zc = Z[(256 - k) & 255];
            const float2 wk = tw[k];
            const float rex = 0.5f * (zk.x + zc.x)
                            + 0.5f * (wk.x * (zk.y + zc.y) - wk.y * (zk.x - zc.x));
            const float v = rex * (1.0f / 512.0f);
            pwr[k] = v * v;
        }
        if (l == 0) {
            const float2 z0 = Z[0];
            const float vn = (z0.x - z0.y) * (1.0f / 512.0f);
            pwr[256] = vn * vn;
        }
        if (l >= 57) pwr[257 + (l - 57)] = 0.0f;   // zero pad 257..263
    }
    __builtin_amdgcn_wave_barrier();

    // Mel: wave-private. Lane l<60: mel = l%20, sub = l/20 (88 bins each).
    // Partial-sum order (sub0+sub1+sub2, float4 fma chain) matches R3 bitwise.
    float acc = 0.0f;
    if (l < 60) {
        const int mel = l % 20;
        const int sub = l / 20;
        const float4* pw4 = (const float4*)pwr + sub * 22;
        const float4* wr4 = (const float4*)(fbP + mel * 264) + sub * 22;
#pragma unroll
        for (int it = 0; it < 22; it++) {
            const float4 p4 = pw4[it];
            const float4 w4 = wr4[it];
            acc = fmaf(w4.x, p4.x, fmaf(w4.y, p4.y,
                  fmaf(w4.z, p4.z, fmaf(w4.w, p4.w, acc))));
        }
    }
    const float p1 = __shfl(acc, l + 20);
    const float p2 = __shfl(acc, l + 40);

    int flag = 0;
    if (l < 20) {
        const float v = acc + p1 + p2;
        float fl;
        if (v < 1e-30f) {                // includes v==0; fp32 underflow risk
            fl = -52.0f;
            flag = 1;
        } else {
            const float l2 = log2f(v);
            fl = floorf(l2);
            flag = (l2 - fl < MARGIN_L2) | ((fl + 1.0f - l2) < MARGIN_L2);
        }
        out[(size_t)fg * 20 + l] = fl;
    }
    const unsigned long long b = __ballot(flag);
    if (worklist) {
        if (l == 0 && b != 0ULL) {
            const unsigned idx = atomicAdd(count, 1u);
            worklist[idx] = (unsigned)fg;
        }
    } else {
        if (l == 0) flags[fg] = (b != 0ULL) ? 1 : 0;
    }
}

// ------------------------------------------- phase 2 (worklist, tier 1) ----
__global__ __launch_bounds__(256) void phase2_wl(
    const float* __restrict__ x,
    const float* __restrict__ fb,
    const float* __restrict__ hw,
    const double* __restrict__ tw64,
    const unsigned* __restrict__ count,
    const unsigned* __restrict__ worklist,
    float* __restrict__ out)
{
    __shared__ double Are[256], Aim[256], Bre[256], Bim[256];
    __shared__ double ltc[256], lts[256];
    __shared__ double pwr[257];

    const int t = threadIdx.x;
    ltc[t] = tw64[t];
    lts[t] = tw64[256 + t];
    __syncthreads();

    const unsigned n = *count;
    for (unsigned i = blockIdx.x; i < n; i += gridDim.x) {
        const int f = (int)worklist[i];

        {
            const float2 xv = ((const float2*)x)[(size_t)f * 256 + t];
            const float2 hv = ((const float2*)hw)[t];
            Are[t] = (double)xv.x * (double)hv.x;
            Aim[t] = (double)xv.y * (double)hv.y;
        }
        __syncthreads();

        double* sre = Are; double* sim = Aim;
        double* dre = Bre; double* dim = Bim;
        const int p = t & 127;
        const int which = t >> 7;
#pragma unroll
        for (int s = 0; s < 8; s++) {
            const int j = p >> s;
            const double ar = sre[p],       ai = sim[p];
            const double br = sre[p + 128], bi = sim[p + 128];
            double orr, oi;
            int dpos;
            if (which) {
                const int idx = j << (s + 1);
                const double wr = ltc[idx];
                const double wi = -lts[idx];
                const double ur = ar - br, ui = ai - bi;
                orr = wr * ur - wi * ui;
                oi  = wr * ui + wi * ur;
                dpos = p + ((j + 1) << s);
            } else {
                orr = ar + br;
                oi  = ai + bi;
                dpos = p + (j << s);
            }
            dre[dpos] = orr;
            dim[dpos] = oi;
            __syncthreads();
            double* tmp;
            tmp = sre; sre = dre; dre = tmp;
            tmp = sim; sim = dim; dim = tmp;
        }

        {
            const double a = sre[t], b = sim[t];
            const int t2 = (256 - t) & 255;
            const double c = sre[t2], d = sim[t2];
            const double rex = 0.5 * (a + c)
                             + 0.5 * (ltc[t] * (b + d) - lts[t] * (a - c));
            const double v = rex * (1.0 / 512.0);
            pwr[t] = v * v;
            if (t == 0) {
                const double vn = (a - b) * (1.0 / 512.0);
                pwr[256] = vn * vn;
            }
        }
        __syncthreads();

        if (t < 160) {
            const int mel = t >> 3;
            const int sub = t & 7;
            const float* wrow = fb + mel * 257;
            double acc = 0.0;
            for (int k = sub; k < 257; k += 8)
                acc = fma((double)wrow[k], pwr[k], acc);
            acc += __shfl_down(acc, 4, 8);
            acc += __shfl_down(acc, 2, 8);
            acc += __shfl_down(acc, 1, 8);
            if (sub == 0) {
                double v = acc;
                if (v == 0.0) v = 2.220446049250313e-16;
                out[(size_t)f * 20 + mel] = (float)floor(log2(v));
            }
        }
        __syncthreads();
    }
}

// ---------------------------------------------- phase 2 (flags, tier 2) ----
__global__ __launch_bounds__(256) void phase2_fix(
    const float* __restrict__ x,
    const float* __restrict__ fb,
    const float* __restrict__ hw,
    const double* __restrict__ tw64,
    const unsigned char* __restrict__ flags,
    float* __restrict__ out)
{
    __shared__ double Are[256], Aim[256], Bre[256], Bim[256];
    __shared__ double ltc[256], lts[256];
    __shared__ double pwr[257];

    const int t = threadIdx.x;
    ltc[t] = tw64[t];
    lts[t] = tw64[256 + t];

    for (int r = 0; r < 8; r++) {
        const int f = blockIdx.x * 8 + r;
        if (!flags[f]) continue;          // block-uniform branch
        __syncthreads();

        {
            const float2 xv = ((const float2*)x)[(size_t)f * 256 + t];
            const float2 hv = ((const float2*)hw)[t];
            Are[t] = (double)xv.x * (double)hv.x;
            Aim[t] = (double)xv.y * (double)hv.y;
        }
        __syncthreads();

        double* sre = Are; double* sim = Aim;
        double* dre = Bre; double* dim = Bim;
        const int p = t & 127;
        const int which = t >> 7;
#pragma unroll
        for (int s = 0; s < 8; s++) {
            const int j = p >> s;
            const double ar = sre[p],       ai = sim[p];
            const double br = sre[p + 128], bi = sim[p + 128];
            double orr, oi;
            int dpos;
            if (which) {
                const int idx = j << (s + 1);
                const double wr = ltc[idx];
                const double wi = -lts[idx];
                const double ur = ar - br, ui = ai - bi;
                orr = wr * ur - wi * ui;
                oi  = wr * ui + wi * ur;
                dpos = p + ((j + 1) << s);
            } else {
                orr = ar + br;
                oi  = ai + bi;
                dpos = p + (j << s);
            }
            dre[dpos] = orr;
            dim[dpos] = oi;
            __syncthreads();
            double* tmp;
            tmp = sre; sre = dre; dre = tmp;
            tmp = sim; sim = dim; dim = tmp;
        }

        {
            const double a = sre[t], b = sim[t];
            const int t2 = (256 - t) & 255;
            const double c = sre[t2], d = sim[t2];
            const double rex = 0.5 * (a + c)
                             + 0.5 * (ltc[t] * (b + d) - lts[t] * (a - c));
            const double v = rex * (1.0 / 512.0);
            pwr[t] = v * v;
            if (t == 0) {
                const double vn = (a - b) * (1.0 / 512.0);
                pwr[256] = vn * vn;
            }
        }
        __syncthreads();

        if (t < 160) {
            const int mel = t >> 3;
            const int sub = t & 7;
            const float* wrow = fb + mel * 257;
            double acc = 0.0;
            for (int k = sub; k < 257; k += 8)
                acc = fma((double)wrow[k], pwr[k], acc);
            acc += __shfl_down(acc, 4, 8);
            acc += __shfl_down(acc, 2, 8);
            acc += __shfl_down(acc, 1, 8);
            if (sub == 0) {
                double v = acc;
                if (v == 0.0) v = 2.220446049250313e-16;
                out[(size_t)f * 20 + mel] = (float)floor(log2(v));
            }
        }
        __syncthreads();
    }
}

// ------------------------------------------------- fallback: all-f64 (R2) ----
__global__ __launch_bounds__(256) void f64_all(
    const float*  __restrict__ x,
    const float*  __restrict__ fb,
    const float*  __restrict__ hw,
    const double* __restrict__ tw,
    float* __restrict__ out)
{
    __shared__ double Are[256], Aim[256], Bre[256], Bim[256];
    __shared__ double ltc[256], lts[256];
    __shared__ double pwr[257];

    const int t = threadIdx.x;
    const int f = blockIdx.x;

    ltc[t] = tw[t];
    lts[t] = tw[256 + t];
    {
        const float2 xv = ((const float2*)x)[(size_t)f * 256 + t];
        const float2 hv = ((const float2*)hw)[t];
        Are[t] = (double)xv.x * (double)hv.x;
        Aim[t] = (double)xv.y * (double)hv.y;
    }
    __syncthreads();

    double* sre = Are; double* sim = Aim;
    double* dre = Bre; double* dim = Bim;
    const int p = t & 127;
    const int which = t >> 7;
#pragma unroll
    for (int s = 0; s < 8; s++) {
        const int j = p >> s;
        const double ar = sre[p],       ai = sim[p];
        const double br = sre[p + 128], bi = sim[p + 128];
        double orr, oi;
        int dpos;
        if (which) {
            const int idx = j << (s + 1);
            const double wr = ltc[idx];
            const double wi = -lts[idx];
            const double ur = ar - br, ui = ai - bi;
            orr = wr * ur - wi * ui;
            oi  = wr * ui + wi * ur;
            dpos = p + ((j + 1) << s);
        } else {
            orr = ar + br;
            oi  = ai + bi;
            dpos = p + (j << s);
        }
        dre[dpos] = orr;
        dim[dpos] = oi;
        __syncthreads();
        double* tmp;
        tmp = sre; sre = dre; dre = tmp;
        tmp = sim; sim = dim; dim = tmp;
    }

    {
        const double a = sre[t], b = sim[t];
        const int t2 = (256 - t) & 255;
        const double c = sre[t2], d = sim[t2];
        const double rex = 0.5 * (a + c)
                         + 0.5 * (ltc[t] * (b + d) - lts[t] * (a - c));
        const double v = rex * (1.0 / 512.0);
        pwr[t] = v * v;
        if (t == 0) {
            const double vn = (a - b) * (1.0 / 512.0);
            pwr[256] = vn * vn;
        }
    }
    __syncthreads();

    if (t < 160) {
        const int mel = t >> 3;
        const int sub = t & 7;
        const float* wrow = fb + mel * 257;
        double acc = 0.0;
        for (int k = sub; k < 257; k += 8)
            acc = fma((double)wrow[k], pwr[k], acc);
        acc += __shfl_down(acc, 4, 8);
        acc += __shfl_down(acc, 2, 8);
        acc += __shfl_down(acc, 1, 8);
        if (sub == 0) {
            double v = acc;
            if (v == 0.0) v = 2.220446049250313e-16;
            out[(size_t)f * 20 + mel] = (float)floor(log2(v));
        }
    }
}

// ---------------------------------------------------------------- launch ----
extern "C" void kernel_launch(void* const* d_in, const int* in_sizes, int n_in,
                              void* d_out, int out_size, void* d_ws, size_t ws_size,
                              hipStream_t stream) {
    const float* x  = (const float*)d_in[0];   // (4096, 32, 512) f32
    const float* fb = (const float*)d_in[1];   // (20, 257) f32
    const float* hw = (const float*)d_in[2];   // (512,) f32
    float* out = (float*)d_out;

    const int frames = in_sizes[0] / 512;      // 131072

    char* ws = (char*)d_ws;
    double* tw64 = (double*)ws;                          // 4096 B
    float2* tw32 = (float2*)(ws + 4096);                 // 2048 B
    float*  fbP  = (float*)(ws + 6144);                  // 21120 B

    const size_t T1 = 32832 + 4 * (size_t)frames;        // count + worklist
    const size_t T2 = 32768 + (size_t)frames;            // flags byte array

    if (ws_size >= T1 && (frames % 4) == 0) {
        unsigned* count    = (unsigned*)(ws + 32768);
        unsigned* worklist = (unsigned*)(ws + 32832);
        prep_full<<<1, 256, 0, stream>>>(fb, tw64, tw32, fbP, count);
        phase1<<<frames / 4, 256, 0, stream>>>(x, hw, tw32, fbP, out,
                                               nullptr, count, worklist);
        phase2_wl<<<2048, 256, 0, stream>>>(x, fb, hw, tw64, count, worklist, out);
    } else if (ws_size >= T2 && (frames % 8) == 0 && (frames % 4) == 0) {
        unsigned char* flags = (unsigned char*)(ws + 32768);
        prep_full<<<1, 256, 0, stream>>>(fb, tw64, tw32, fbP, nullptr);
        phase1<<<frames / 4, 256, 0, stream>>>(x, hw, tw32, fbP, out,
                                               flags, nullptr, nullptr);
        phase2_fix<<<frames / 8, 256, 0, stream>>>(x, fb, hw, tw64, flags, out);
    } else {
        prep_tw64<<<1, 256, 0, stream>>>(tw64);
        f64_all<<<frames, 256, 0, stream>>>(x, fb, hw, tw64, out);
    }
}

// Round 5
// 459.156 us; speedup vs baseline: 1.7245x; 1.1289x over previous
//
#include <hip/hip_runtime.h>
#include <math.h>

// AudioPreprocessingLayer: hamming * x -> rfft(512, norm=forward).real^2
//   -> mel(20x257) -> where(==0, 2^-52) -> floor(log2)
//
// Hybrid scheme:
//   prep:   twiddle tables (f64+f32), padded filter bank, worklist count=0
//   phase1: fp32, TWO frames per wave (float4-interleaved LDS: element e =
//           (f0.re,f0.im,f1.re,f1.im)), 4 waves/block = 8 frames/block.
//           Stage 0 runs from registers (no initial LDS round-trip).
//           +1-per-8 float4 padding makes every stage conflict-free.
//           Frames with any log2(mel) within 1e-3 of an integer (or
//           mel<1e-30) are appended to a compacted worklist.
//   phase2: 4096 blocks grid-stride the worklist; each flagged frame (~4%)
//           recomputed with the R2-validated f64 pipeline.

#define MARGIN_L2 1.0e-3f
#define IDX(e) ((e) + ((e) >> 3))   // float4 units: pad 1 per 8 elements

__device__ __forceinline__ float4 f4add(float4 a, float4 b) {
    return make_float4(a.x + b.x, a.y + b.y, a.z + b.z, a.w + b.w);
}
__device__ __forceinline__ float4 f4sub(float4 a, float4 b) {
    return make_float4(a.x - b.x, a.y - b.y, a.z - b.z, a.w - b.w);
}
// w=(cos,sin) meaning e^{-i*theta}; applied to both packed complex values
__device__ __forceinline__ float4 cmulc4(float2 w, float4 z) {
    return make_float4(w.x * z.x + w.y * z.y, w.x * z.y - w.y * z.x,
                       w.x * z.z + w.y * z.w, w.x * z.w - w.y * z.z);
}

// Fused radix-2^2 butterfly (validated R3 formulas), packed 2 frames.
__device__ __forceinline__ void bfly4(int s, int l, const float2* tw,
                                      float4 x1, float4 y1, float4 x2, float4 y2,
                                      float4* dst) {
    const int j = l >> s;
    const int r = l & ((1 << s) - 1);
    const float2 w1 = tw[j << (s + 1)];
    const float2 w2 = tw[j << (s + 2)];
    const float4 u1 = f4add(x1, y1);
    const float4 v1 = cmulc4(w1, f4sub(x1, y1));
    const float4 u2 = f4add(x2, y2);
    const float4 m  = cmulc4(w1, f4sub(x2, y2));
    const float4 v2 = make_float4(m.y, -m.x, m.w, -m.z);   // -i * m
    const float4 o0 = f4add(u1, u2);
    const float4 o1 = cmulc4(w2, f4sub(u1, u2));
    const float4 o2 = f4add(v1, v2);
    const float4 o3 = cmulc4(w2, f4sub(v1, v2));
    const int eb = (j << (s + 2)) + r;
    dst[IDX(eb)]            = o0;
    dst[IDX(eb + (1 << s))] = o2;
    dst[IDX(eb + (2 << s))] = o1;
    dst[IDX(eb + (3 << s))] = o3;
}

// ---------------------------------------------------------------- prep ----
__global__ void prep_full(const float* __restrict__ fb,
                          double* __restrict__ tw64,
                          float2* __restrict__ tw32,
                          float* __restrict__ fbP,
                          unsigned* count) {
    const int t = threadIdx.x;  // 256
    double s, c;
    sincospi((double)t * (1.0 / 256.0), &s, &c);
    tw64[t]       = c;
    tw64[256 + t] = s;
    tw32[t] = make_float2((float)c, (float)s);
    for (int i = t; i < 20 * 264; i += 256) {
        const int m = i / 264, k = i % 264;
        fbP[i] = (k < 257) ? fb[m * 257 + k] : 0.0f;  // rows padded to 264
    }
    if (count && t == 0) *count = 0;
}

__global__ void prep_tw64(double* __restrict__ tw64) {
    const int t = threadIdx.x;
    double s, c;
    sincospi((double)t * (1.0 / 256.0), &s, &c);
    tw64[t]       = c;
    tw64[256 + t] = s;
}

// -------------------------------------------------------------- phase 1 ----
// fp32: 2 frames per wave, 4 waves per 256-thread block (8 frames/block).
__global__ __launch_bounds__(256, 4) void phase1(
    const float* __restrict__ x,      // (frames, 512)
    const float* __restrict__ hw,     // (512,)
    const float2* __restrict__ tw32,  // (256,) (cos,sin) of pi*k/256 (ws)
    const float* __restrict__ fbP,    // (20, 264) padded filter bank (ws)
    float* __restrict__ out,          // (frames, 20)
    unsigned* __restrict__ count,     // worklist count
    unsigned* __restrict__ worklist)  // flagged frame ids
{
    __shared__ __align__(16) float4 Abuf[4][288];   // 288 = IDX(255)+2 pad
    __shared__ __align__(16) float4 Bbuf[4][288];
    __shared__ __align__(16) float2 tw[256];

    const int t = threadIdx.x;
    const int w = t >> 6;     // wave id = frame-pair slot
    const int l = t & 63;     // lane
    const int fg0 = (blockIdx.x * 4 + w) * 2;
    const int fg1 = fg0 + 1;

    tw[t] = tw32[t];
    __syncthreads();   // tw ready (A/B are wave-private)

    float4* A = &Abuf[w][0];
    float4* B = &Bbuf[w][0];

    // Load + window + stage s=0 directly from registers -> B.
    // Element e holds (f0.re, f0.im, f1.re, f1.im); x1=e[l], x2=e[l+64],
    // y1=e[l+128], y2=e[l+192] -- exactly what stage 0 consumes.
    {
        const float2* xa = (const float2*)(x + (size_t)fg0 * 512);
        const float2* xb = (const float2*)(x + (size_t)fg1 * 512);
        const float2* hp = (const float2*)hw;
        const float2 h0 = hp[l],       h1 = hp[l + 64];
        const float2 h2 = hp[l + 128], h3 = hp[l + 192];
        const float2 a0 = xa[l],       a1 = xa[l + 64];
        const float2 a2 = xa[l + 128], a3 = xa[l + 192];
        const float2 b0 = xb[l],       b1 = xb[l + 64];
        const float2 b2 = xb[l + 128], b3 = xb[l + 192];
        const float4 x1 = make_float4(a0.x * h0.x, a0.y * h0.y,
                                      b0.x * h0.x, b0.y * h0.y);
        const float4 x2 = make_float4(a1.x * h1.x, a1.y * h1.y,
                                      b1.x * h1.x, b1.y * h1.y);
        const float4 y1 = make_float4(a2.x * h2.x, a2.y * h2.y,
                                      b2.x * h2.x, b2.y * h2.y);
        const float4 y2 = make_float4(a3.x * h3.x, a3.y * h3.y,
                                      b3.x * h3.x, b3.y * h3.y);
        bfly4(0, l, tw, x1, y1, x2, y2, B);
    }
    __builtin_amdgcn_wave_barrier();   // in-wave DS order; pin compiler

    // Stages s = 2, 4, 6: B->A, A->B, B->A.
    float4* src = B;
    float4* dst = A;
#pragma unroll
    for (int s = 2; s <= 6; s += 2) {
        const float4 x1 = src[IDX(l)];
        const float4 y1 = src[IDX(l + 128)];
        const float4 x2 = src[IDX(l + 64)];
        const float4 y2 = src[IDX(l + 192)];
        bfly4(s, l, tw, x1, y1, x2, y2, dst);
        __builtin_amdgcn_wave_barrier();
        float4* tmp = src; src = dst; dst = tmp;
    }
    // Result (natural order) in A (== src); B free -> pwr lives there.

    // Untangle -> Re(rfft)_k, /512, square (validated formula), both frames.
    float2* pwr2 = (float2*)B;        // 264 float2, unpadded
    {
        const float4* Z = A;
#pragma unroll
        for (int i = 0; i < 4; i++) {
            const int k = l + 64 * i;
            const float4 zk = Z[IDX(k)];
            const float4 zc = Z[IDX((256 - k) & 255)];
            const float2 wk = tw[k];
            const float rexA = 0.5f * (zk.x + zc.x)
                             + 0.5f * (wk.x * (zk.y + zc.y) - wk.y * (zk.x - zc.x));
            const float rexB = 0.5f * (zk.z + zc.z)
                             + 0.5f * (wk.x * (zk.w + zc.w) - wk.y * (zk.z - zc.z));
            const float vA = rexA * (1.0f / 512.0f);
            const float vB = rexB * (1.0f / 512.0f);
            pwr2[k] = make_float2(vA * vA, vB * vB);
        }
        if (l == 0) {
            const float4 z0 = Z[IDX(0)];
            const float vA = (z0.x - z0.y) * (1.0f / 512.0f);
            const float vB = (z0.z - z0.w) * (1.0f / 512.0f);
            pwr2[256] = make_float2(vA * vA, vB * vB);
        }
        if (l >= 57) pwr2[257 + (l - 57)] = make_float2(0.0f, 0.0f);
    }
    __builtin_amdgcn_wave_barrier();

    // Mel: lanes l<60: mel = l%20, sub = l/20 (88 bins each); one fb float4
    // (4 bins) serves BOTH frames; pwr pair j = bins 2j,2j+1 both frames.
    float accA = 0.0f, accB = 0.0f;
    if (l < 60) {
        const int mel = l % 20;
        const int sub = l / 20;
        const float4* fb4 = (const float4*)(fbP + mel * 264) + sub * 22;
        const float4* pw4 = (const float4*)pwr2 + sub * 44;
#pragma unroll
        for (int it = 0; it < 22; it++) {
            const float4 w4 = fb4[it];
            const float4 q0 = pw4[2 * it];       // (f0[4T],f1[4T],f0[4T+1],f1[4T+1])
            const float4 q1 = pw4[2 * it + 1];   // bins 4T+2, 4T+3
            accA = fmaf(w4.w, q1.z, fmaf(w4.z, q1.x,
                   fmaf(w4.y, q0.z, fmaf(w4.x, q0.x, accA))));
            accB = fmaf(w4.w, q1.w, fmaf(w4.z, q1.y,
                   fmaf(w4.y, q0.w, fmaf(w4.x, q0.y, accB))));
        }
    }
    const float pA1 = __shfl(accA, l + 20);
    const float pA2 = __shfl(accA, l + 40);
    const float pB1 = __shfl(accB, l + 20);
    const float pB2 = __shfl(accB, l + 40);

    int flagA = 0, flagB = 0;
    if (l < 20) {
        const float vA = accA + pA1 + pA2;
        float flA;
        if (vA < 1e-30f) { flA = -52.0f; flagA = 1; }
        else {
            const float l2 = log2f(vA);
            flA = floorf(l2);
            flagA = (l2 - flA < MARGIN_L2) | ((flA + 1.0f - l2) < MARGIN_L2);
        }
        out[(size_t)fg0 * 20 + l] = flA;

        const float vB = accB + pB1 + pB2;
        float flB;
        if (vB < 1e-30f) { flB = -52.0f; flagB = 1; }
        else {
            const float l2 = log2f(vB);
            flB = floorf(l2);
            flagB = (l2 - flB < MARGIN_L2) | ((flB + 1.0f - l2) < MARGIN_L2);
        }
        out[(size_t)fg1 * 20 + l] = flB;
    }
    const unsigned long long bA = __ballot(flagA);
    const unsigned long long bB = __ballot(flagB);
    if (l == 0) {
        const unsigned nf = (bA != 0ULL) + (bB != 0ULL);
        if (nf) {
            unsigned idx = atomicAdd(count, nf);
            if (bA != 0ULL) worklist[idx++] = (unsigned)fg0;
            if (bB != 0ULL) worklist[idx]   = (unsigned)fg1;
        }
    }
}

// ------------------------------------------- phase 2 (worklist repair) ----
__global__ __launch_bounds__(256) void phase2_wl(
    const float* __restrict__ x,
    const float* __restrict__ fb,
    const float* __restrict__ hw,
    const double* __restrict__ tw64,
    const unsigned* __restrict__ count,
    const unsigned* __restrict__ worklist,
    float* __restrict__ out)
{
    __shared__ double Are[256], Aim[256], Bre[256], Bim[256];
    __shared__ double ltc[256], lts[256];
    __shared__ double pwr[257];

    const int t = threadIdx.x;
    ltc[t] = tw64[t];
    lts[t] = tw64[256 + t];
    __syncthreads();

    const unsigned n = *count;
    for (unsigned i = blockIdx.x; i < n; i += gridDim.x) {
        const int f = (int)worklist[i];

        {
            const float2 xv = ((const float2*)x)[(size_t)f * 256 + t];
            const float2 hv = ((const float2*)hw)[t];
            Are[t] = (double)xv.x * (double)hv.x;
            Aim[t] = (double)xv.y * (double)hv.y;
        }
        __syncthreads();

        double* sre = Are; double* sim = Aim;
        double* dre = Bre; double* dim = Bim;
        const int p = t & 127;
        const int which = t >> 7;
#pragma unroll
        for (int s = 0; s < 8; s++) {
            const int j = p >> s;
            const double ar = sre[p],       ai = sim[p];
            const double br = sre[p + 128], bi = sim[p + 128];
            double orr, oi;
            int dpos;
            if (which) {
                const int idx = j << (s + 1);
                const double wr = ltc[idx];
                const double wi = -lts[idx];
                const double ur = ar - br, ui = ai - bi;
                orr = wr * ur - wi * ui;
                oi  = wr * ui + wi * ur;
                dpos = p + ((j + 1) << s);
            } else {
                orr = ar + br;
                oi  = ai + bi;
                dpos = p + (j << s);
            }
            dre[dpos] = orr;
            dim[dpos] = oi;
            __syncthreads();
            double* tmp;
            tmp = sre; sre = dre; dre = tmp;
            tmp = sim; sim = dim; dim = tmp;
        }

        {
            const double a = sre[t], b = sim[t];
            const int t2 = (256 - t) & 255;
            const double c = sre[t2], d = sim[t2];
            const double rex = 0.5 * (a + c)
                             + 0.5 * (ltc[t] * (b + d) - lts[t] * (a - c));
            const double v = rex * (1.0 / 512.0);
            pwr[t] = v * v;
            if (t == 0) {
                const double vn = (a - b) * (1.0 / 512.0);
                pwr[256] = vn * vn;
            }
        }
        __syncthreads();

        if (t < 160) {
            const int mel = t >> 3;
            const int sub = t & 7;
            const float* wrow = fb + mel * 257;
            double acc = 0.0;
            for (int k = sub; k < 257; k += 8)
                acc = fma((double)wrow[k], pwr[k], acc);
            acc += __shfl_down(acc, 4, 8);
            acc += __shfl_down(acc, 2, 8);
            acc += __shfl_down(acc, 1, 8);
            if (sub == 0) {
                double v = acc;
                if (v == 0.0) v = 2.220446049250313e-16;
                out[(size_t)f * 20 + mel] = (float)floor(log2(v));
            }
        }
        __syncthreads();
    }
}

// ------------------------------------------------- fallback: all-f64 (R2) ----
__global__ __launch_bounds__(256) void f64_all(
    const float*  __restrict__ x,
    const float*  __restrict__ fb,
    const float*  __restrict__ hw,
    const double* __restrict__ tw,
    float* __restrict__ out)
{
    __shared__ double Are[256], Aim[256], Bre[256], Bim[256];
    __shared__ double ltc[256], lts[256];
    __shared__ double pwr[257];

    const int t = threadIdx.x;
    const int f = blockIdx.x;

    ltc[t] = tw[t];
    lts[t] = tw[256 + t];
    {
        const float2 xv = ((const float2*)x)[(size_t)f * 256 + t];
        const float2 hv = ((const float2*)hw)[t];
        Are[t] = (double)xv.x * (double)hv.x;
        Aim[t] = (double)xv.y * (double)hv.y;
    }
    __syncthreads();

    double* sre = Are; double* sim = Aim;
    double* dre = Bre; double* dim = Bim;
    const int p = t & 127;
    const int which = t >> 7;
#pragma unroll
    for (int s = 0; s < 8; s++) {
        const int j = p >> s;
        const double ar = sre[p],       ai = sim[p];
        const double br = sre[p + 128], bi = sim[p + 128];
        double orr, oi;
        int dpos;
        if (which) {
            const int idx = j << (s + 1);
            const double wr = ltc[idx];
            const double wi = -lts[idx];
            const double ur = ar - br, ui = ai - bi;
            orr = wr * ur - wi * ui;
            oi  = wr * ui + wi * ur;
            dpos = p + ((j + 1) << s);
        } else {
            orr = ar + br;
            oi  = ai + bi;
            dpos = p + (j << s);
        }
        dre[dpos] = orr;
        dim[dpos] = oi;
        __syncthreads();
        double* tmp;
        tmp = sre; sre = dre; dre = tmp;
        tmp = sim; sim = dim; dim = tmp;
    }

    {
        const double a = sre[t], b = sim[t];
        const int t2 = (256 - t) & 255;
        const double c = sre[t2], d = sim[t2];
        const double rex = 0.5 * (a + c)
                         + 0.5 * (ltc[t] * (b + d) - lts[t] * (a - c));
        const double v = rex * (1.0 / 512.0);
        pwr[t] = v * v;
        if (t == 0) {
            const double vn = (a - b) * (1.0 / 512.0);
            pwr[256] = vn * vn;
        }
    }
    __syncthreads();

    if (t < 160) {
        const int mel = t >> 3;
        const int sub = t & 7;
        const float* wrow = fb + mel * 257;
        double acc = 0.0;
        for (int k = sub; k < 257; k += 8)
            acc = fma((double)wrow[k], pwr[k], acc);
        acc += __shfl_down(acc, 4, 8);
        acc += __shfl_down(acc, 2, 8);
        acc += __shfl_down(acc, 1, 8);
        if (sub == 0) {
            double v = acc;
            if (v == 0.0) v = 2.220446049250313e-16;
            out[(size_t)f * 20 + mel] = (float)floor(log2(v));
        }
    }
}

// ---------------------------------------------------------------- launch ----
extern "C" void kernel_launch(void* const* d_in, const int* in_sizes, int n_in,
                              void* d_out, int out_size, void* d_ws, size_t ws_size,
                              hipStream_t stream) {
    const float* x  = (const float*)d_in[0];   // (4096, 32, 512) f32
    const float* fb = (const float*)d_in[1];   // (20, 257) f32
    const float* hw = (const float*)d_in[2];   // (512,) f32
    float* out = (float*)d_out;

    const int frames = in_sizes[0] / 512;      // 131072

    char* ws = (char*)d_ws;
    double* tw64 = (double*)ws;                          // 4096 B
    float2* tw32 = (float2*)(ws + 4096);                 // 2048 B
    float*  fbP  = (float*)(ws + 6144);                  // 21120 B

    const size_t T1 = 32832 + 4 * (size_t)frames;        // count + worklist

    if (ws_size >= T1 && (frames % 8) == 0) {
        unsigned* count    = (unsigned*)(ws + 32768);
        unsigned* worklist = (unsigned*)(ws + 32832);
        prep_full<<<1, 256, 0, stream>>>(fb, tw64, tw32, fbP, count);
        phase1<<<frames / 8, 256, 0, stream>>>(x, hw, tw32, fbP, out,
                                               count, worklist);
        phase2_wl<<<4096, 256, 0, stream>>>(x, fb, hw, tw64, count, worklist, out);
    } else {
        prep_tw64<<<1, 256, 0, stream>>>(tw64);
        f64_all<<<frames, 256, 0, stream>>>(x, fb, hw, tw64, out);
    }
}